// Round 2
// baseline (5688.357 us; speedup 1.0000x reference)
//
#include <hip/hip_runtime.h>
#include <cstddef>

#define B_   8
#define N_   8192
#define M_   2048
#define K_   32
#define DIN_ 13

// ---------------------------------------------------------------------------
// Kernel 1: farthest point sampling, one block per batch cloud.
// 1024 threads, 8 points per thread held in registers. Per step:
//   update mind -> wave argmax (shfl) -> 16 wave candidates in LDS ->
//   single barrier (parity double-buffer) -> redundant 16-way tree reduce.
// Tie-break everywhere: max value, then SMALLEST index (jnp.argmax = first max).
// ---------------------------------------------------------------------------
__global__ __launch_bounds__(1024) void fps_kernel(
    const float* __restrict__ pos,     // [B, N, 3]
    float* __restrict__ pos_s,         // [B, M, 3]
    float* __restrict__ batch_s)       // [B, M]
{
  const int b    = blockIdx.x;
  const int t    = threadIdx.x;
  const int lane = t & 63;
  const int wv   = t >> 6;                  // wave id 0..15
  const float* p = pos + (size_t)b * N_ * 3;

  // batch_s[b, m] = b for all m (batch input is broadcast arange(B))
  for (int mm = t; mm < M_; mm += 1024)
    batch_s[b * M_ + mm] = (float)b;

  float px[8], py[8], pz[8], mind[8];
#pragma unroll
  for (int i = 0; i < 8; ++i) {
    int j = t + 1024 * i;
    px[i] = p[j * 3 + 0];
    py[i] = p[j * 3 + 1];
    pz[i] = p[j * 3 + 2];
    mind[i] = 1e10f;
  }

  __shared__ float candv[2][16];
  __shared__ int   candj[2][16];
  __shared__ float candx[2][16];
  __shared__ float candy[2][16];
  __shared__ float candz[2][16];

  float lx = p[0], ly = p[1], lz = p[2];    // first sample = index 0
  if (t == 0) {
    pos_s[(size_t)b * M_ * 3 + 0] = lx;
    pos_s[(size_t)b * M_ * 3 + 1] = ly;
    pos_s[(size_t)b * M_ * 3 + 2] = lz;
  }

  for (int s = 1; s < M_; ++s) {
    float bv = -1.0f; int bj = 0;
    float bx = 0.f, by = 0.f, bz = 0.f;
    {
#pragma clang fp contract(off)
#pragma unroll
      for (int i = 0; i < 8; ++i) {
        float dx = px[i] - lx, dy = py[i] - ly, dz = pz[i] - lz;
        float d  = (dx * dx + dy * dy) + dz * dz;   // match jnp sum order, no fma
        float m2 = mind[i] < d ? mind[i] : d;
        mind[i]  = m2;
        // strict > keeps earliest i (smallest index within this thread)
        if (m2 > bv) { bv = m2; bj = t + 1024 * i; bx = px[i]; by = py[i]; bz = pz[i]; }
      }
    }
    // wave-level argmax over 64 lanes, carrying winner's coordinates
#pragma unroll
    for (int off = 1; off < 64; off <<= 1) {
      float ov = __shfl_xor(bv, off);
      int   oj = __shfl_xor(bj, off);
      float ox = __shfl_xor(bx, off);
      float oy = __shfl_xor(by, off);
      float oz = __shfl_xor(bz, off);
      if (ov > bv || (ov == bv && oj < bj)) { bv = ov; bj = oj; bx = ox; by = oy; bz = oz; }
    }
    const int par = s & 1;
    if (lane == 0) {
      candv[par][wv] = bv; candj[par][wv] = bj;
      candx[par][wv] = bx; candy[par][wv] = by; candz[par][wv] = bz;
    }
    __syncthreads();
    // every thread redundantly reduces the 16 candidates (no 2nd barrier:
    // next step writes the other parity buffer)
    float cv[16]; int cj[16];
#pragma unroll
    for (int q = 0; q < 16; ++q) { cv[q] = candv[par][q]; cj[q] = candj[par][q]; }
#pragma unroll
    for (int st = 8; st > 0; st >>= 1) {
#pragma unroll
      for (int q = 0; q < st; ++q) {
        bool take = (cv[q + st] > cv[q]) ||
                    (cv[q + st] == cv[q] && cj[q + st] < cj[q]);
        if (take) { cv[q] = cv[q + st]; cj[q] = cj[q + st]; }
      }
    }
    const int wj = cj[0];
    const int qw = (wj >> 6) & 15;        // winning wave id = ((wj & 1023) >> 6)
    lx = candx[par][qw]; ly = candy[par][qw]; lz = candz[par][qw];
    if (t == 0) {
      size_t o = ((size_t)b * M_ + s) * 3;
      pos_s[o + 0] = lx; pos_s[o + 1] = ly; pos_s[o + 2] = lz;
    }
  }
}

// ---------------------------------------------------------------------------
// Kernel 2: ball query + gather + MLP(16->64->128, relu) + masked max.
// One wave (64 threads) per sampled point.
// ---------------------------------------------------------------------------
__global__ __launch_bounds__(64, 2) void sa_kernel(
    const float* __restrict__ x,       // [B, N, 13]
    const float* __restrict__ pos,     // [B, N, 3]
    const float* __restrict__ W1,      // [16, 64]
    const float* __restrict__ b1,      // [64]
    const float* __restrict__ W2,      // [64, 128]
    const float* __restrict__ b2,      // [128]
    const float* __restrict__ pos_s,   // [B, M, 3]
    float* __restrict__ x_out)         // [B, M, 128]
{
  const int blk  = blockIdx.x;
  const int b    = blk >> 11;          // / 2048
  const int m    = blk & 2047;
  const int lane = threadIdx.x;

  __shared__ int   nbr[K_];
  __shared__ float feat[K_ * 16];      // [32][16]
  __shared__ float h1s[K_ * 64];       // [32][64]

  const float* pb = pos + (size_t)b * N_ * 3;
  const float* xb = x   + (size_t)b * N_ * DIN_;
  const size_t so = ((size_t)b * M_ + m) * 3;
  const float sx = pos_s[so + 0];
  const float sy = pos_s[so + 1];
  const float sz = pos_s[so + 2];
  const float R2 = (float)(0.2 * 0.2);   // match JAX weak-typed scalar cast

  // --- ball query: first K in-ball neighbors in index order ---
  int cnt = 0;
  for (int base = 0; base < N_ && cnt < K_; base += 64) {
    int j = base + lane;
    float qx = pb[j * 3 + 0], qy = pb[j * 3 + 1], qz = pb[j * 3 + 2];
    bool win;
    {
#pragma clang fp contract(off)
      float dx = sx - qx, dy = sy - qy, dz = sz - qz;
      float d2 = (dx * dx + dy * dy) + dz * dz;
      win = d2 <= R2;
    }
    unsigned long long mk = __ballot(win);
    int rank = (int)__popcll(mk & ((1ull << lane) - 1ull));
    if (win) {
      int slot = cnt + rank;
      if (slot < K_) nbr[slot] = j;
    }
    cnt += (int)__popcll(mk);
  }
  const int valid = cnt < K_ ? cnt : K_;   // >= 1 (center is its own neighbor)
  __syncthreads();

  // --- gather features [32][16] = concat(x_j, pos_j - pos_s) ---
  for (int tq = lane; tq < K_ * 16; tq += 64) {
    int r = tq >> 4, i = tq & 15;
    float v = 0.f;
    if (r < valid) {
      int j = nbr[r];
      if (i < DIN_) {
        v = xb[j * DIN_ + i];
      } else {
        float c = (i == 13) ? sx : (i == 14) ? sy : sz;
        float q = pb[j * 3 + (i - 13)];
        v = q - c;   // plain subtract — nothing to contract
      }
    }
    feat[tq] = v;
  }
  __syncthreads();

  // --- MLP layer 1: [32,16] @ [16,64], lane = output column ---
  float w1c[16];
#pragma unroll
  for (int i = 0; i < 16; ++i) w1c[i] = W1[i * 64 + lane];
  const float bb1 = b1[lane];
#pragma unroll 4
  for (int r = 0; r < K_; ++r) {
    const float4* fr = (const float4*)&feat[r * 16];
    float4 f0 = fr[0], f1 = fr[1], f2 = fr[2], f3 = fr[3];
    float a = bb1;
    a += f0.x * w1c[0];  a += f0.y * w1c[1];  a += f0.z * w1c[2];  a += f0.w * w1c[3];
    a += f1.x * w1c[4];  a += f1.y * w1c[5];  a += f1.z * w1c[6];  a += f1.w * w1c[7];
    a += f2.x * w1c[8];  a += f2.y * w1c[9];  a += f2.z * w1c[10]; a += f2.w * w1c[11];
    a += f3.x * w1c[12]; a += f3.y * w1c[13]; a += f3.z * w1c[14]; a += f3.w * w1c[15];
    h1s[r * 64 + lane] = a > 0.f ? a : 0.f;
  }
  __syncthreads();

  // --- MLP layer 2: [32,64] @ [64,128]; lane owns cols lane and lane+64 ---
  float w2a[64], w2b[64];
#pragma unroll
  for (int k = 0; k < 64; ++k) {
    w2a[k] = W2[k * 128 + lane];
    w2b[k] = W2[k * 128 + 64 + lane];
  }
  const float bb2a = b2[lane];
  const float bb2b = b2[64 + lane];
  float mx0 = -INFINITY, mx1 = -INFINITY;
  for (int r = 0; r < valid; ++r) {
    const float4* hr = (const float4*)&h1s[r * 64];
    float a0 = bb2a, a1 = bb2b;
#pragma unroll
    for (int kq = 0; kq < 16; ++kq) {
      float4 h = hr[kq];
      a0 += h.x * w2a[4 * kq + 0];  a1 += h.x * w2b[4 * kq + 0];
      a0 += h.y * w2a[4 * kq + 1];  a1 += h.y * w2b[4 * kq + 1];
      a0 += h.z * w2a[4 * kq + 2];  a1 += h.z * w2b[4 * kq + 2];
      a0 += h.w * w2a[4 * kq + 3];  a1 += h.w * w2b[4 * kq + 3];
    }
    a0 = a0 > 0.f ? a0 : 0.f;
    a1 = a1 > 0.f ? a1 : 0.f;
    mx0 = fmaxf(mx0, a0);
    mx1 = fmaxf(mx1, a1);
  }
  float* o = x_out + ((size_t)b * M_ + m) * 128;
  o[lane]      = mx0;
  o[64 + lane] = mx1;
}

// ---------------------------------------------------------------------------
extern "C" void kernel_launch(void* const* d_in, const int* in_sizes, int n_in,
                              void* d_out, int out_size, void* d_ws, size_t ws_size,
                              hipStream_t stream) {
  (void)in_sizes; (void)n_in; (void)d_ws; (void)ws_size; (void)out_size;
  const float* x   = (const float*)d_in[0];
  const float* pos = (const float*)d_in[1];
  // d_in[2] = batch (unused: always broadcast arange(B))
  const float* W1  = (const float*)d_in[3];
  const float* b1  = (const float*)d_in[4];
  const float* W2  = (const float*)d_in[5];
  const float* b2  = (const float*)d_in[6];

  float* out     = (float*)d_out;
  float* x_out   = out;                                  // [B, M, 128]
  float* pos_s   = out + (size_t)B_ * M_ * 128;          // [B, M, 3]
  float* batch_s = pos_s + (size_t)B_ * M_ * 3;          // [B, M]

  fps_kernel<<<B_, 1024, 0, stream>>>(pos, pos_s, batch_s);
  sa_kernel<<<B_ * M_, 64, 0, stream>>>(x, pos, W1, b1, W2, b2, pos_s, x_out);
}

// Round 3
// 2559.020 us; speedup vs baseline: 2.2229x; 2.2229x over previous
//
#include <hip/hip_runtime.h>
#include <cstddef>

#define B_   8
#define N_   8192
#define M_   2048
#define K_   32
#define DIN_ 13

// ---------------------------------------------------------------------------
// Kernel 1: farthest point sampling, one block of 256 threads per batch cloud.
// 32 points/thread in registers. Per step:
//   register mind update + in-thread argmax  (~700 cyc VALU floor)
//   wave argmax via packed u64 key, 6 shfl stages x 2 DS ops  (~450 cyc)
//   4 wave candidates in LDS, parity double-buffer, ONE barrier  (~250 cyc)
//   winner coords re-fetched from global (L2-resident)  (~200 cyc)
// Key = (float_bits(v) << 32) | (0xFFFFFFFF - j): u64 max == (max v, min j),
// exactly jnp.argmax first-max tie-break (valid since v >= 0).
// ---------------------------------------------------------------------------
__global__ __launch_bounds__(256) void fps_kernel(
    const float* __restrict__ pos,     // [B, N, 3]
    float* __restrict__ pos_s,         // [B, M, 3]
    float* __restrict__ batch_s)       // [B, M]
{
  const int b    = blockIdx.x;
  const int t    = threadIdx.x;
  const int lane = t & 63;
  const int wv   = t >> 6;                  // wave id 0..3
  const float* p = pos + (size_t)b * N_ * 3;

  // batch_s[b, m] = b for all m (batch input is broadcast arange(B))
  for (int mm = t; mm < M_; mm += 256)
    batch_s[b * M_ + mm] = (float)b;

  float px[32], py[32], pz[32], mind[32];
#pragma unroll
  for (int i = 0; i < 32; ++i) {
    int j = t + 256 * i;
    px[i] = p[j * 3 + 0];
    py[i] = p[j * 3 + 1];
    pz[i] = p[j * 3 + 2];
    mind[i] = 1e10f;
  }

  __shared__ alignas(16) unsigned long long candk[2][4];

  float lx = p[0], ly = p[1], lz = p[2];    // first sample = index 0
  if (t == 0) {
    pos_s[(size_t)b * M_ * 3 + 0] = lx;
    pos_s[(size_t)b * M_ * 3 + 1] = ly;
    pos_s[(size_t)b * M_ * 3 + 2] = lz;
  }

  for (int s = 1; s < M_; ++s) {
    float bv = -1.0f; int bi = 0;
    {
#pragma clang fp contract(off)
#pragma unroll
      for (int i = 0; i < 32; ++i) {
        float dx = px[i] - lx, dy = py[i] - ly, dz = pz[i] - lz;
        float d  = (dx * dx + dy * dy) + dz * dz;   // match jnp sum order, no fma
        float m2 = fminf(mind[i], d);
        mind[i]  = m2;
        bool g   = m2 > bv;      // strict > keeps earliest i (= smallest j)
        bv = g ? m2 : bv;
        bi = g ? i  : bi;
      }
    }
    const int bj = t + (bi << 8);
    unsigned long long key =
        ((unsigned long long)__float_as_uint(bv) << 32) |
        (unsigned int)(0xFFFFFFFFu - (unsigned int)bj);
    // wave-level u64-max reduce: 6 stages, 2 DS ops each
#pragma unroll
    for (int off = 1; off < 64; off <<= 1) {
      unsigned long long ok = __shfl_xor(key, off);
      key = ok > key ? ok : key;
    }
    const int par = s & 1;
    if (lane == 0) candk[par][wv] = key;
    __syncthreads();
    // redundant 4-way reduce in all threads (no 2nd barrier: parity buffer)
    unsigned long long k0 = candk[par][0], k1 = candk[par][1];
    unsigned long long k2 = candk[par][2], k3 = candk[par][3];
    k0 = k1 > k0 ? k1 : k0;
    k2 = k3 > k2 ? k3 : k2;
    k0 = k2 > k0 ? k2 : k0;
    const int wj = (int)(0xFFFFFFFFu - (unsigned int)(k0 & 0xFFFFFFFFull));
    // winner coords from global (L2-resident: 96 KB/batch per CU)
    lx = p[wj * 3 + 0]; ly = p[wj * 3 + 1]; lz = p[wj * 3 + 2];
    if (t == 0) {
      size_t o = ((size_t)b * M_ + s) * 3;
      pos_s[o + 0] = lx; pos_s[o + 1] = ly; pos_s[o + 2] = lz;
    }
  }
}

// ---------------------------------------------------------------------------
// Kernel 2: ball query + gather + MLP(16->64->128, relu) + masked max.
// One wave (64 threads) per sampled point.  (unchanged this round)
// ---------------------------------------------------------------------------
__global__ __launch_bounds__(64, 2) void sa_kernel(
    const float* __restrict__ x,       // [B, N, 13]
    const float* __restrict__ pos,     // [B, N, 3]
    const float* __restrict__ W1,      // [16, 64]
    const float* __restrict__ b1,      // [64]
    const float* __restrict__ W2,      // [64, 128]
    const float* __restrict__ b2,      // [128]
    const float* __restrict__ pos_s,   // [B, M, 3]
    float* __restrict__ x_out)         // [B, M, 128]
{
  const int blk  = blockIdx.x;
  const int b    = blk >> 11;          // / 2048
  const int m    = blk & 2047;
  const int lane = threadIdx.x;

  __shared__ int   nbr[K_];
  __shared__ float feat[K_ * 16];      // [32][16]
  __shared__ float h1s[K_ * 64];       // [32][64]

  const float* pb = pos + (size_t)b * N_ * 3;
  const float* xb = x   + (size_t)b * N_ * DIN_;
  const size_t so = ((size_t)b * M_ + m) * 3;
  const float sx = pos_s[so + 0];
  const float sy = pos_s[so + 1];
  const float sz = pos_s[so + 2];
  const float R2 = (float)(0.2 * 0.2);   // match JAX weak-typed scalar cast

  // --- ball query: first K in-ball neighbors in index order ---
  int cnt = 0;
  for (int base = 0; base < N_ && cnt < K_; base += 64) {
    int j = base + lane;
    float qx = pb[j * 3 + 0], qy = pb[j * 3 + 1], qz = pb[j * 3 + 2];
    bool win;
    {
#pragma clang fp contract(off)
      float dx = sx - qx, dy = sy - qy, dz = sz - qz;
      float d2 = (dx * dx + dy * dy) + dz * dz;
      win = d2 <= R2;
    }
    unsigned long long mk = __ballot(win);
    int rank = (int)__popcll(mk & ((1ull << lane) - 1ull));
    if (win) {
      int slot = cnt + rank;
      if (slot < K_) nbr[slot] = j;
    }
    cnt += (int)__popcll(mk);
  }
  const int valid = cnt < K_ ? cnt : K_;   // >= 1 (center is its own neighbor)
  __syncthreads();

  // --- gather features [32][16] = concat(x_j, pos_j - pos_s) ---
  for (int tq = lane; tq < K_ * 16; tq += 64) {
    int r = tq >> 4, i = tq & 15;
    float v = 0.f;
    if (r < valid) {
      int j = nbr[r];
      if (i < DIN_) {
        v = xb[j * DIN_ + i];
      } else {
        float c = (i == 13) ? sx : (i == 14) ? sy : sz;
        float q = pb[j * 3 + (i - 13)];
        v = q - c;   // plain subtract — nothing to contract
      }
    }
    feat[tq] = v;
  }
  __syncthreads();

  // --- MLP layer 1: [32,16] @ [16,64], lane = output column ---
  float w1c[16];
#pragma unroll
  for (int i = 0; i < 16; ++i) w1c[i] = W1[i * 64 + lane];
  const float bb1 = b1[lane];
#pragma unroll 4
  for (int r = 0; r < K_; ++r) {
    const float4* fr = (const float4*)&feat[r * 16];
    float4 f0 = fr[0], f1 = fr[1], f2 = fr[2], f3 = fr[3];
    float a = bb1;
    a += f0.x * w1c[0];  a += f0.y * w1c[1];  a += f0.z * w1c[2];  a += f0.w * w1c[3];
    a += f1.x * w1c[4];  a += f1.y * w1c[5];  a += f1.z * w1c[6];  a += f1.w * w1c[7];
    a += f2.x * w1c[8];  a += f2.y * w1c[9];  a += f2.z * w1c[10]; a += f2.w * w1c[11];
    a += f3.x * w1c[12]; a += f3.y * w1c[13]; a += f3.z * w1c[14]; a += f3.w * w1c[15];
    h1s[r * 64 + lane] = a > 0.f ? a : 0.f;
  }
  __syncthreads();

  // --- MLP layer 2: [32,64] @ [64,128]; lane owns cols lane and lane+64 ---
  float w2a[64], w2b[64];
#pragma unroll
  for (int k = 0; k < 64; ++k) {
    w2a[k] = W2[k * 128 + lane];
    w2b[k] = W2[k * 128 + 64 + lane];
  }
  const float bb2a = b2[lane];
  const float bb2b = b2[64 + lane];
  float mx0 = -INFINITY, mx1 = -INFINITY;
  for (int r = 0; r < valid; ++r) {
    const float4* hr = (const float4*)&h1s[r * 64];
    float a0 = bb2a, a1 = bb2b;
#pragma unroll
    for (int kq = 0; kq < 16; ++kq) {
      float4 h = hr[kq];
      a0 += h.x * w2a[4 * kq + 0];  a1 += h.x * w2b[4 * kq + 0];
      a0 += h.y * w2a[4 * kq + 1];  a1 += h.y * w2b[4 * kq + 1];
      a0 += h.z * w2a[4 * kq + 2];  a1 += h.z * w2b[4 * kq + 2];
      a0 += h.w * w2a[4 * kq + 3];  a1 += h.w * w2b[4 * kq + 3];
    }
    a0 = a0 > 0.f ? a0 : 0.f;
    a1 = a1 > 0.f ? a1 : 0.f;
    mx0 = fmaxf(mx0, a0);
    mx1 = fmaxf(mx1, a1);
  }
  float* o = x_out + ((size_t)b * M_ + m) * 128;
  o[lane]      = mx0;
  o[64 + lane] = mx1;
}

// ---------------------------------------------------------------------------
extern "C" void kernel_launch(void* const* d_in, const int* in_sizes, int n_in,
                              void* d_out, int out_size, void* d_ws, size_t ws_size,
                              hipStream_t stream) {
  (void)in_sizes; (void)n_in; (void)d_ws; (void)ws_size; (void)out_size;
  const float* x   = (const float*)d_in[0];
  const float* pos = (const float*)d_in[1];
  // d_in[2] = batch (unused: always broadcast arange(B))
  const float* W1  = (const float*)d_in[3];
  const float* b1  = (const float*)d_in[4];
  const float* W2  = (const float*)d_in[5];
  const float* b2  = (const float*)d_in[6];

  float* out     = (float*)d_out;
  float* x_out   = out;                                  // [B, M, 128]
  float* pos_s   = out + (size_t)B_ * M_ * 128;          // [B, M, 3]
  float* batch_s = pos_s + (size_t)B_ * M_ * 3;          // [B, M]

  fps_kernel<<<B_, 256, 0, stream>>>(pos, pos_s, batch_s);
  sa_kernel<<<B_ * M_, 64, 0, stream>>>(x, pos, W1, b1, W2, b2, pos_s, x_out);
}

// Round 4
// 2495.624 us; speedup vs baseline: 2.2793x; 1.0254x over previous
//
#include <hip/hip_runtime.h>
#include <cstddef>

#define B_   8
#define N_   8192
#define M_   2048
#define K_   32
#define DIN_ 13

// DPP-assisted max step: combine v with the value DPP-moved from another lane.
// Invalid source lanes yield old = -inf (identity for max). VALU-pipe only.
template <int CTRL>
__device__ __forceinline__ float dppmax(float v) {
  int o = __builtin_amdgcn_update_dpp(
      (int)0xff800000, __float_as_int(v), CTRL, 0xF, 0xF, false);
  return fmaxf(v, __int_as_float(o));
}

// ---------------------------------------------------------------------------
// Kernel 1: farthest point sampling. One 1024-thread block per batch cloud;
// 8 points/thread fully register-resident (round-2 proved no spill: VGPR 48).
// Per step:
//   1) dist+min update of 8 register points, in-thread 8-way max tree (VALU)
//   2) wave max via DPP row_shr 1/2/4/8 + row_bcast15/31 -> lane 63 (VALU)
//   3) lane63: LDS atomicMax(int bits of f32; valid since mind >= 0)
//   4) barrier A; read blockmax; rescan 8 values for == blockmax (exact:
//      fmaxf/DPP-max propagate an input bit-exactly); matching thread (rare)
//      atomicMin(index) -> smallest global index == jnp.argmax first-max.
//   5) barrier B; read winner index; scalar-load coords (L2-resident).
// Parity-doubled slots; resets target the opposite-parity slot inside the
// [A,B] region, so every slot access is barrier-ordered (no races).
// ---------------------------------------------------------------------------
__global__ __launch_bounds__(1024) void fps_kernel(
    const float* __restrict__ pos,     // [B, N, 3]
    float* __restrict__ pos_s,         // [B, M, 3]
    float* __restrict__ batch_s)       // [B, M]
{
  const int b    = blockIdx.x;
  const int t    = threadIdx.x;
  const int lane = t & 63;
  const float* p = pos + (size_t)b * N_ * 3;

  // batch_s[b, m] = b (batch input is broadcast arange(B))
  for (int mm = t; mm < M_; mm += 1024)
    batch_s[b * M_ + mm] = (float)b;

  float px[8], py[8], pz[8], mind[8];
#pragma unroll
  for (int i = 0; i < 8; ++i) {
    int j = t + 1024 * i;
    px[i] = p[j * 3 + 0];
    py[i] = p[j * 3 + 1];
    pz[i] = p[j * 3 + 2];
    mind[i] = 1e10f;
  }

  __shared__ int          bmax[2];     // blockmax as int bits (f32 >= 0)
  __shared__ unsigned int jslot[2];    // winner index (min over matches)
  if (t == 0) {
    bmax[0] = 0; bmax[1] = 0;
    jslot[0] = 0xFFFFFFFFu; jslot[1] = 0xFFFFFFFFu;
  }

  float lx = p[0], ly = p[1], lz = p[2];    // first sample = index 0
  if (t == 0) {
    pos_s[(size_t)b * M_ * 3 + 0] = lx;
    pos_s[(size_t)b * M_ * 3 + 1] = ly;
    pos_s[(size_t)b * M_ * 3 + 2] = lz;
  }
  __syncthreads();

  for (int s = 1; s < M_; ++s) {
    const int par = s & 1;
    float tmax;
    {
#pragma clang fp contract(off)
#pragma unroll
      for (int i = 0; i < 8; ++i) {
        float dx = px[i] - lx, dy = py[i] - ly, dz = pz[i] - lz;
        float d  = (dx * dx + dy * dy) + dz * dz;   // jnp sum order, no fma
        mind[i]  = fminf(mind[i], d);
      }
      float m0 = fmaxf(mind[0], mind[1]), m1 = fmaxf(mind[2], mind[3]);
      float m2 = fmaxf(mind[4], mind[5]), m3 = fmaxf(mind[6], mind[7]);
      tmax = fmaxf(fmaxf(m0, m1), fmaxf(m2, m3));
    }
    // wave max (VALU-pipe DPP): lane 63 ends with the full 64-lane max
    float w = tmax;
    w = dppmax<0x111>(w);   // row_shr:1
    w = dppmax<0x112>(w);   // row_shr:2
    w = dppmax<0x114>(w);   // row_shr:4
    w = dppmax<0x118>(w);   // row_shr:8
    w = dppmax<0x142>(w);   // row_bcast:15
    w = dppmax<0x143>(w);   // row_bcast:31
    if (lane == 63) atomicMax(&bmax[par], __float_as_int(w));
    __syncthreads();                               // barrier A
    const float bm = __int_as_float(bmax[par]);
    if (t == 0) {                                  // reset OTHER-parity slots
      bmax[par ^ 1]  = 0;
      jslot[par ^ 1] = 0xFFFFFFFFu;
    }
    // rescan: smallest global index with mind == blockmax (exact equality)
    unsigned int jc = 0xFFFFFFFFu;
#pragma unroll
    for (int i = 7; i >= 0; --i)
      if (mind[i] == bm) jc = (unsigned int)(t + 1024 * i);
    if (jc != 0xFFFFFFFFu) atomicMin(&jslot[par], jc);
    __syncthreads();                               // barrier B
    const int wj = (int)__builtin_amdgcn_readfirstlane((int)jslot[par]);
    lx = p[wj * 3 + 0]; ly = p[wj * 3 + 1]; lz = p[wj * 3 + 2];
    if (t == 0) {
      size_t o = ((size_t)b * M_ + s) * 3;
      pos_s[o + 0] = lx; pos_s[o + 1] = ly; pos_s[o + 2] = lz;
    }
  }
}

// ---------------------------------------------------------------------------
// Kernel 2: ball query + gather + MLP(16->64->128, relu) + masked max.
// One wave (64 threads) per sampled point.  (unchanged this round)
// ---------------------------------------------------------------------------
__global__ __launch_bounds__(64, 2) void sa_kernel(
    const float* __restrict__ x,       // [B, N, 13]
    const float* __restrict__ pos,     // [B, N, 3]
    const float* __restrict__ W1,      // [16, 64]
    const float* __restrict__ b1,      // [64]
    const float* __restrict__ W2,      // [64, 128]
    const float* __restrict__ b2,      // [128]
    const float* __restrict__ pos_s,   // [B, M, 3]
    float* __restrict__ x_out)         // [B, M, 128]
{
  const int blk  = blockIdx.x;
  const int b    = blk >> 11;          // / 2048
  const int m    = blk & 2047;
  const int lane = threadIdx.x;

  __shared__ int   nbr[K_];
  __shared__ float feat[K_ * 16];      // [32][16]
  __shared__ float h1s[K_ * 64];       // [32][64]

  const float* pb = pos + (size_t)b * N_ * 3;
  const float* xb = x   + (size_t)b * N_ * DIN_;
  const size_t so = ((size_t)b * M_ + m) * 3;
  const float sx = pos_s[so + 0];
  const float sy = pos_s[so + 1];
  const float sz = pos_s[so + 2];
  const float R2 = (float)(0.2 * 0.2);   // match JAX weak-typed scalar cast

  // --- ball query: first K in-ball neighbors in index order ---
  int cnt = 0;
  for (int base = 0; base < N_ && cnt < K_; base += 64) {
    int j = base + lane;
    float qx = pb[j * 3 + 0], qy = pb[j * 3 + 1], qz = pb[j * 3 + 2];
    bool win;
    {
#pragma clang fp contract(off)
      float dx = sx - qx, dy = sy - qy, dz = sz - qz;
      float d2 = (dx * dx + dy * dy) + dz * dz;
      win = d2 <= R2;
    }
    unsigned long long mk = __ballot(win);
    int rank = (int)__popcll(mk & ((1ull << lane) - 1ull));
    if (win) {
      int slot = cnt + rank;
      if (slot < K_) nbr[slot] = j;
    }
    cnt += (int)__popcll(mk);
  }
  const int valid = cnt < K_ ? cnt : K_;   // >= 1 (center is its own neighbor)
  __syncthreads();

  // --- gather features [32][16] = concat(x_j, pos_j - pos_s) ---
  for (int tq = lane; tq < K_ * 16; tq += 64) {
    int r = tq >> 4, i = tq & 15;
    float v = 0.f;
    if (r < valid) {
      int j = nbr[r];
      if (i < DIN_) {
        v = xb[j * DIN_ + i];
      } else {
        float c = (i == 13) ? sx : (i == 14) ? sy : sz;
        float q = pb[j * 3 + (i - 13)];
        v = q - c;   // plain subtract — nothing to contract
      }
    }
    feat[tq] = v;
  }
  __syncthreads();

  // --- MLP layer 1: [32,16] @ [16,64], lane = output column ---
  float w1c[16];
#pragma unroll
  for (int i = 0; i < 16; ++i) w1c[i] = W1[i * 64 + lane];
  const float bb1 = b1[lane];
#pragma unroll 4
  for (int r = 0; r < K_; ++r) {
    const float4* fr = (const float4*)&feat[r * 16];
    float4 f0 = fr[0], f1 = fr[1], f2 = fr[2], f3 = fr[3];
    float a = bb1;
    a += f0.x * w1c[0];  a += f0.y * w1c[1];  a += f0.z * w1c[2];  a += f0.w * w1c[3];
    a += f1.x * w1c[4];  a += f1.y * w1c[5];  a += f1.z * w1c[6];  a += f1.w * w1c[7];
    a += f2.x * w1c[8];  a += f2.y * w1c[9];  a += f2.z * w1c[10]; a += f2.w * w1c[11];
    a += f3.x * w1c[12]; a += f3.y * w1c[13]; a += f3.z * w1c[14]; a += f3.w * w1c[15];
    h1s[r * 64 + lane] = a > 0.f ? a : 0.f;
  }
  __syncthreads();

  // --- MLP layer 2: [32,64] @ [64,128]; lane owns cols lane and lane+64 ---
  float w2a[64], w2b[64];
#pragma unroll
  for (int k = 0; k < 64; ++k) {
    w2a[k] = W2[k * 128 + lane];
    w2b[k] = W2[k * 128 + 64 + lane];
  }
  const float bb2a = b2[lane];
  const float bb2b = b2[64 + lane];
  float mx0 = -INFINITY, mx1 = -INFINITY;
  for (int r = 0; r < valid; ++r) {
    const float4* hr = (const float4*)&h1s[r * 64];
    float a0 = bb2a, a1 = bb2b;
#pragma unroll
    for (int kq = 0; kq < 16; ++kq) {
      float4 h = hr[kq];
      a0 += h.x * w2a[4 * kq + 0];  a1 += h.x * w2b[4 * kq + 0];
      a0 += h.y * w2a[4 * kq + 1];  a1 += h.y * w2b[4 * kq + 1];
      a0 += h.z * w2a[4 * kq + 2];  a1 += h.z * w2b[4 * kq + 2];
      a0 += h.w * w2a[4 * kq + 3];  a1 += h.w * w2b[4 * kq + 3];
    }
    a0 = a0 > 0.f ? a0 : 0.f;
    a1 = a1 > 0.f ? a1 : 0.f;
    mx0 = fmaxf(mx0, a0);
    mx1 = fmaxf(mx1, a1);
  }
  float* o = x_out + ((size_t)b * M_ + m) * 128;
  o[lane]      = mx0;
  o[64 + lane] = mx1;
}

// ---------------------------------------------------------------------------
extern "C" void kernel_launch(void* const* d_in, const int* in_sizes, int n_in,
                              void* d_out, int out_size, void* d_ws, size_t ws_size,
                              hipStream_t stream) {
  (void)in_sizes; (void)n_in; (void)d_ws; (void)ws_size; (void)out_size;
  const float* x   = (const float*)d_in[0];
  const float* pos = (const float*)d_in[1];
  // d_in[2] = batch (unused: always broadcast arange(B))
  const float* W1  = (const float*)d_in[3];
  const float* b1  = (const float*)d_in[4];
  const float* W2  = (const float*)d_in[5];
  const float* b2  = (const float*)d_in[6];

  float* out     = (float*)d_out;
  float* x_out   = out;                                  // [B, M, 128]
  float* pos_s   = out + (size_t)B_ * M_ * 128;          // [B, M, 3]
  float* batch_s = pos_s + (size_t)B_ * M_ * 3;          // [B, M]

  fps_kernel<<<B_, 1024, 0, stream>>>(pos, pos_s, batch_s);
  sa_kernel<<<B_ * M_, 64, 0, stream>>>(x, pos, W1, b1, W2, b2, pos_s, x_out);
}